// Round 1
// baseline (165.926 us; speedup 1.0000x reference)
//
#include <hip/hip_runtime.h>

#define NN 1024
#define DFEAT 6
#define TSTEPS 60
#define HID 64
#define RREL 60

// ---------------- Kernel 1: GRU over time, one node per block ----------------
// Block = 192 threads (3 waves). Thread g owns gate-output g in [0,192):
//   gi[g] = b_ih[g] + sum_d x_t[d] * W_ih[g][d]
//   gh[g] = b_hh[g] + sum_k h[k]  * W_hh[g][k]   (W_hh row g held in 64 VGPRs)
// h broadcast from LDS as float4 (conflict-free broadcast reads).
__global__ __launch_bounds__(192) void gru_kernel(
    const float* __restrict__ x,      // (1024, 360)  x[n][d*60 + t]
    const float* __restrict__ W_ih,   // (192, 6)
    const float* __restrict__ W_hh,   // (192, 64)
    const float* __restrict__ b_ih,   // (192)
    const float* __restrict__ b_hh,   // (192)
    const float* __restrict__ w_att,  // (188)
    float* __restrict__ h_last,       // (1024, 64)
    float* __restrict__ s_i,          // (1024)
    float* __restrict__ s_j)          // (1024)
{
    const int n = blockIdx.x;
    const int g = threadIdx.x;

    __shared__ __align__(16) float x_sh[DFEAT * TSTEPS];
    __shared__ __align__(16) float h_sh[HID];
    __shared__ float gi_sh[192];
    __shared__ float gh_sh[192];

    // stage x row
    for (int idx = g; idx < DFEAT * TSTEPS; idx += 192)
        x_sh[idx] = x[(size_t)n * (DFEAT * TSTEPS) + idx];

    // W_hh row g -> registers
    float whh[HID];
#pragma unroll
    for (int k4 = 0; k4 < HID / 4; ++k4) {
        float4 w = *reinterpret_cast<const float4*>(&W_hh[g * HID + k4 * 4]);
        whh[k4 * 4 + 0] = w.x; whh[k4 * 4 + 1] = w.y;
        whh[k4 * 4 + 2] = w.z; whh[k4 * 4 + 3] = w.w;
    }
    float wih[DFEAT];
#pragma unroll
    for (int d = 0; d < DFEAT; ++d) wih[d] = W_ih[g * DFEAT + d];
    const float bih = b_ih[g];
    const float bhh = b_hh[g];

    if (g < HID) h_sh[g] = 0.0f;
    __syncthreads();

    for (int t = 0; t < TSTEPS; ++t) {
        float gi = bih;
#pragma unroll
        for (int d = 0; d < DFEAT; ++d) gi += x_sh[d * TSTEPS + t] * wih[d];

        float gh = bhh;
#pragma unroll
        for (int k4 = 0; k4 < HID / 4; ++k4) {
            float4 hv = *reinterpret_cast<const float4*>(&h_sh[k4 * 4]); // broadcast
            gh += hv.x * whh[k4 * 4 + 0] + hv.y * whh[k4 * 4 + 1]
                + hv.z * whh[k4 * 4 + 2] + hv.w * whh[k4 * 4 + 3];
        }
        gi_sh[g] = gi;
        gh_sh[g] = gh;
        __syncthreads();

        if (g < HID) {
            float ir = gi_sh[g],        hr = gh_sh[g];
            float iz = gi_sh[HID + g],  hz = gh_sh[HID + g];
            float in_ = gi_sh[2*HID + g], hn = gh_sh[2*HID + g];
            float r = 1.0f / (1.0f + __expf(-(ir + hr)));
            float z = 1.0f / (1.0f + __expf(-(iz + hz)));
            float nn_ = tanhf(in_ + r * hn);
            float hold = h_sh[g];
            h_sh[g] = (1.0f - z) * nn_ + z * hold;
        }
        __syncthreads();
    }

    if (g < HID) {
        float hv = h_sh[g];
        h_last[(size_t)n * HID + g] = hv;
        float pi = hv * w_att[g];
        float pj = hv * w_att[HID + g];
#pragma unroll
        for (int off = 32; off > 0; off >>= 1) {
            pi += __shfl_down(pi, off);
            pj += __shfl_down(pj, off);
        }
        if (g == 0) { s_i[n] = pi; s_j[n] = pj; }
    }
}

// ---------------- Kernel 2: relation reduce + softmax + agg + FC -------------
// One block (256 threads) per output row i. Streams rel[i][*][*] (240 KB).
__global__ __launch_bounds__(256) void attn_kernel(
    const float* __restrict__ rel,    // (1024, 1024, 60)
    const float* __restrict__ w_att,  // (188): w_rel = w_att[128..188)
    const float* __restrict__ b_att,  // (1)
    const float* __restrict__ W_fc,   // (128)
    const float* __restrict__ b_fc,   // (1)
    const float* __restrict__ h_last, // (1024, 64)
    const float* __restrict__ s_i,    // (1024)
    const float* __restrict__ s_j,    // (1024)
    float* __restrict__ out)          // (1024)
{
    const int i = blockIdx.x;
    const int tid = threadIdx.x;

    __shared__ __align__(16) float temp_sh[NN];   // temp, then e*mask
    __shared__ float red_sh[256];

    // w_rel -> registers (aligned: byte offset 512)
    float wrel[RREL];
#pragma unroll
    for (int r4 = 0; r4 < RREL / 4; ++r4) {
        float4 w = *reinterpret_cast<const float4*>(&w_att[2 * HID + r4 * 4]);
        wrel[r4 * 4 + 0] = w.x; wrel[r4 * 4 + 1] = w.y;
        wrel[r4 * 4 + 2] = w.z; wrel[r4 * 4 + 3] = w.w;
    }
    const float si_b = s_i[i] + b_att[0];

    float maskc[4];
    float local_max = -3.0e38f;
#pragma unroll
    for (int c = 0; c < 4; ++c) {
        const int j = tid + c * 256;
        const float4* rp = reinterpret_cast<const float4*>(&rel[((size_t)i * NN + j) * RREL]);
        float srel = 0.0f, msum = 0.0f;
#pragma unroll
        for (int r4 = 0; r4 < RREL / 4; ++r4) {
            float4 v = rp[r4];
            srel += v.x * wrel[r4*4+0] + v.y * wrel[r4*4+1]
                  + v.z * wrel[r4*4+2] + v.w * wrel[r4*4+3];
            msum += v.x + v.y + v.z + v.w;
        }
        float w = si_b + s_j[j] + srel;
        w = (w >= 0.0f) ? w : 0.01f * w;
        maskc[c] = (msum != 0.0f) ? 1.0f : 0.0f;
        float tv = maskc[c] * w;
        tv = (tv == 0.0f) ? -10000.0f : tv;
        temp_sh[j] = tv;
        local_max = fmaxf(local_max, tv);
    }

    // block-reduce max
    red_sh[tid] = local_max;
    __syncthreads();
    for (int s = 128; s > 0; s >>= 1) {
        if (tid < s) red_sh[tid] = fmaxf(red_sh[tid], red_sh[tid + s]);
        __syncthreads();
    }
    const float M = red_sh[0];
    __syncthreads();

    // exp, masked-store, block-reduce sum (denominator over ALL j, as reference)
    float lsum = 0.0f;
#pragma unroll
    for (int c = 0; c < 4; ++c) {
        const int j = tid + c * 256;
        float e = __expf(temp_sh[j] - M);
        lsum += e;
        temp_sh[j] = e * maskc[c];
    }
    red_sh[tid] = lsum;
    __syncthreads();
    for (int s = 128; s > 0; s >>= 1) {
        if (tid < s) red_sh[tid] += red_sh[tid + s];
        __syncthreads();
    }
    const float invS = 1.0f / red_sh[0];
    __syncthreads();

    // agg[h] = invS * sum_j pm[j] * h_last[j][h]
    const int h = tid & (HID - 1);
    const int grp = tid >> 6;           // 4 groups of 256 j's
    float part = 0.0f;
    const float* hl = h_last + (size_t)grp * 256 * HID + h;
    const float* pm = temp_sh + grp * 256;
    for (int jc = 0; jc < 256; ++jc)
        part += pm[jc] * hl[(size_t)jc * HID];

    red_sh[tid] = part;
    __syncthreads();

    if (tid < HID) {
        float agg = (red_sh[tid] + red_sh[HID + tid]
                   + red_sh[2 * HID + tid] + red_sh[3 * HID + tid]) * invS;
        float o = h_last[(size_t)i * HID + tid] * W_fc[tid] + agg * W_fc[HID + tid];
#pragma unroll
        for (int off = 32; off > 0; off >>= 1) o += __shfl_down(o, off);
        if (tid == 0) out[i] = o + b_fc[0];
    }
}

extern "C" void kernel_launch(void* const* d_in, const int* in_sizes, int n_in,
                              void* d_out, int out_size, void* d_ws, size_t ws_size,
                              hipStream_t stream) {
    const float* x     = (const float*)d_in[0];
    const float* rel   = (const float*)d_in[1];
    const float* W_ih  = (const float*)d_in[2];
    const float* W_hh  = (const float*)d_in[3];
    const float* b_ih  = (const float*)d_in[4];
    const float* b_hh  = (const float*)d_in[5];
    const float* w_att = (const float*)d_in[6];
    const float* b_att = (const float*)d_in[7];
    const float* W_fc  = (const float*)d_in[8];
    const float* b_fc  = (const float*)d_in[9];

    float* ws     = (float*)d_ws;
    float* h_last = ws;                 // 1024*64
    float* s_i    = ws + NN * HID;      // 1024
    float* s_j    = ws + NN * HID + NN; // 1024

    gru_kernel<<<NN, 192, 0, stream>>>(x, W_ih, W_hh, b_ih, b_hh, w_att,
                                       h_last, s_i, s_j);
    attn_kernel<<<NN, 256, 0, stream>>>(rel, w_att, b_att, W_fc, b_fc,
                                        h_last, s_i, s_j, (float*)d_out);
}

// Round 2
// 131.449 us; speedup vs baseline: 1.2623x; 1.2623x over previous
//
#include <hip/hip_runtime.h>

#define NN 1024
#define DFEAT 6
#define TSTEPS 60
#define HID 64
#define RREL 60

// ---------------- Kernel 1: GRU over time, one node per block ----------------
__global__ __launch_bounds__(192) void gru_kernel(
    const float* __restrict__ x,      // (1024, 360)  x[n][d*60 + t]
    const float* __restrict__ W_ih,   // (192, 6)
    const float* __restrict__ W_hh,   // (192, 64)
    const float* __restrict__ b_ih,   // (192)
    const float* __restrict__ b_hh,   // (192)
    const float* __restrict__ w_att,  // (188)
    float* __restrict__ h_last,       // (1024, 64)
    float* __restrict__ s_i,          // (1024)
    float* __restrict__ s_j)          // (1024)
{
    const int n = blockIdx.x;
    const int g = threadIdx.x;

    __shared__ __align__(16) float x_sh[DFEAT * TSTEPS];
    __shared__ __align__(16) float h_sh[HID];
    __shared__ float gi_sh[192];
    __shared__ float gh_sh[192];

    for (int idx = g; idx < DFEAT * TSTEPS; idx += 192)
        x_sh[idx] = x[(size_t)n * (DFEAT * TSTEPS) + idx];

    float whh[HID];
#pragma unroll
    for (int k4 = 0; k4 < HID / 4; ++k4) {
        float4 w = *reinterpret_cast<const float4*>(&W_hh[g * HID + k4 * 4]);
        whh[k4 * 4 + 0] = w.x; whh[k4 * 4 + 1] = w.y;
        whh[k4 * 4 + 2] = w.z; whh[k4 * 4 + 3] = w.w;
    }
    float wih[DFEAT];
#pragma unroll
    for (int d = 0; d < DFEAT; ++d) wih[d] = W_ih[g * DFEAT + d];
    const float bih = b_ih[g];
    const float bhh = b_hh[g];

    if (g < HID) h_sh[g] = 0.0f;
    __syncthreads();

    for (int t = 0; t < TSTEPS; ++t) {
        float gi = bih;
#pragma unroll
        for (int d = 0; d < DFEAT; ++d) gi += x_sh[d * TSTEPS + t] * wih[d];

        float gh = bhh;
#pragma unroll
        for (int k4 = 0; k4 < HID / 4; ++k4) {
            float4 hv = *reinterpret_cast<const float4*>(&h_sh[k4 * 4]); // broadcast
            gh += hv.x * whh[k4 * 4 + 0] + hv.y * whh[k4 * 4 + 1]
                + hv.z * whh[k4 * 4 + 2] + hv.w * whh[k4 * 4 + 3];
        }
        gi_sh[g] = gi;
        gh_sh[g] = gh;
        __syncthreads();

        if (g < HID) {
            float ir = gi_sh[g],        hr = gh_sh[g];
            float iz = gi_sh[HID + g],  hz = gh_sh[HID + g];
            float in_ = gi_sh[2*HID + g], hn = gh_sh[2*HID + g];
            float r = 1.0f / (1.0f + __expf(-(ir + hr)));
            float z = 1.0f / (1.0f + __expf(-(iz + hz)));
            float nn_ = tanhf(in_ + r * hn);
            float hold = h_sh[g];
            h_sh[g] = (1.0f - z) * nn_ + z * hold;
        }
        __syncthreads();
    }

    if (g < HID) {
        float hv = h_sh[g];
        h_last[(size_t)n * HID + g] = hv;
        float pi = hv * w_att[g];
        float pj = hv * w_att[HID + g];
#pragma unroll
        for (int off = 32; off > 0; off >>= 1) {
            pi += __shfl_down(pi, off);
            pj += __shfl_down(pj, off);
        }
        if (g == 0) { s_i[n] = pi; s_j[n] = pj; }
    }
}

// ------------- Kernel 2: stream rel, write pre-softmax temp (4 MB) -----------
// One thread per (i,j) pair. 4096 blocks x 256 threads = 16 blocks/CU.
// Only 15 float4 loads in flight per thread; wrel in SGPRs (uniform loads).
__global__ __launch_bounds__(256) void rel_kernel(
    const float* __restrict__ rel,    // (1024, 1024, 60)
    const float* __restrict__ w_att,  // (188)
    const float* __restrict__ b_att,  // (1)
    const float* __restrict__ s_i,    // (1024)
    const float* __restrict__ s_j,    // (1024)
    float* __restrict__ temp)         // (1024, 1024)
{
    const int b = blockIdx.x;                 // 4096
    const int i = b >> 2;
    const int j = ((b & 3) << 8) + threadIdx.x;
    const size_t pair = (size_t)i * NN + j;

    float wrel[RREL];                          // uniform -> scalar regs
#pragma unroll
    for (int r = 0; r < RREL; ++r) wrel[r] = w_att[2 * HID + r];
    const float si_b = s_i[i] + b_att[0];      // uniform per block

    const float4* rp = reinterpret_cast<const float4*>(rel + pair * RREL);
    float srel = 0.0f, msum = 0.0f;
#pragma unroll
    for (int r4 = 0; r4 < RREL / 4; ++r4) {
        float4 v = rp[r4];
        srel += v.x * wrel[4*r4+0] + v.y * wrel[4*r4+1]
              + v.z * wrel[4*r4+2] + v.w * wrel[4*r4+3];
        msum += v.x + v.y + v.z + v.w;
    }
    float w = si_b + s_j[j] + srel;
    w = (w >= 0.0f) ? w : 0.01f * w;
    float tv = (msum != 0.0f) ? w : 0.0f;      // mask * weight
    tv = (tv == 0.0f) ? -10000.0f : tv;        // sentinel == mask info
    temp[pair] = tv;
}

// --------- Kernel 3: per-row softmax + agg matvec + final FC -----------------
__global__ __launch_bounds__(256) void row_kernel(
    const float* __restrict__ temp,   // (1024, 1024)
    const float* __restrict__ h_last, // (1024, 64)
    const float* __restrict__ W_fc,   // (128)
    const float* __restrict__ b_fc,   // (1)
    float* __restrict__ out)          // (1024)
{
    const int i = blockIdx.x;
    const int tid = threadIdx.x;

    __shared__ __align__(16) float pm_sh[NN];
    __shared__ float red_sh[256];

    float4 tv = reinterpret_cast<const float4*>(temp + (size_t)i * NN)[tid];
    float m = fmaxf(fmaxf(tv.x, tv.y), fmaxf(tv.z, tv.w));
    red_sh[tid] = m;
    __syncthreads();
    for (int s = 128; s > 0; s >>= 1) {
        if (tid < s) red_sh[tid] = fmaxf(red_sh[tid], red_sh[tid + s]);
        __syncthreads();
    }
    const float M = red_sh[0];
    __syncthreads();

    float4 e;
    e.x = __expf(tv.x - M); e.y = __expf(tv.y - M);
    e.z = __expf(tv.z - M); e.w = __expf(tv.w - M);
    const float lsum = e.x + e.y + e.z + e.w;   // denom over ALL j (reference)
    float4 pmv;                                  // numerator masked
    pmv.x = (tv.x != -10000.0f) ? e.x : 0.0f;
    pmv.y = (tv.y != -10000.0f) ? e.y : 0.0f;
    pmv.z = (tv.z != -10000.0f) ? e.z : 0.0f;
    pmv.w = (tv.w != -10000.0f) ? e.w : 0.0f;
    reinterpret_cast<float4*>(pm_sh)[tid] = pmv;

    red_sh[tid] = lsum;
    __syncthreads();
    for (int s = 128; s > 0; s >>= 1) {
        if (tid < s) red_sh[tid] += red_sh[tid + s];
        __syncthreads();
    }
    const float invS = 1.0f / red_sh[0];
    __syncthreads();

    // agg[h] = invS * sum_j pm[j] * h_last[j][h]
    const int h = tid & (HID - 1);
    const int grp = tid >> 6;                    // 4 groups x 256 j each
    float part = 0.0f;
    const float* hl = h_last + (size_t)grp * 256 * HID + h;
    const float* pm = pm_sh + grp * 256;
    for (int jc = 0; jc < 256; ++jc)
        part += pm[jc] * hl[(size_t)jc * HID];

    red_sh[tid] = part;
    __syncthreads();

    if (tid < HID) {
        float agg = (red_sh[tid] + red_sh[HID + tid]
                   + red_sh[2 * HID + tid] + red_sh[3 * HID + tid]) * invS;
        float o = h_last[(size_t)i * HID + tid] * W_fc[tid] + agg * W_fc[HID + tid];
#pragma unroll
        for (int off = 32; off > 0; off >>= 1) o += __shfl_down(o, off);
        if (tid == 0) out[i] = o + b_fc[0];
    }
}

extern "C" void kernel_launch(void* const* d_in, const int* in_sizes, int n_in,
                              void* d_out, int out_size, void* d_ws, size_t ws_size,
                              hipStream_t stream) {
    const float* x     = (const float*)d_in[0];
    const float* rel   = (const float*)d_in[1];
    const float* W_ih  = (const float*)d_in[2];
    const float* W_hh  = (const float*)d_in[3];
    const float* b_ih  = (const float*)d_in[4];
    const float* b_hh  = (const float*)d_in[5];
    const float* w_att = (const float*)d_in[6];
    const float* b_att = (const float*)d_in[7];
    const float* W_fc  = (const float*)d_in[8];
    const float* b_fc  = (const float*)d_in[9];

    float* ws     = (float*)d_ws;
    float* h_last = ws;                      // 1024*64
    float* s_i    = ws + NN * HID;           // 1024
    float* s_j    = ws + NN * HID + NN;      // 1024
    float* temp   = ws + NN * HID + 2 * NN;  // 1024*1024

    gru_kernel<<<NN, 192, 0, stream>>>(x, W_ih, W_hh, b_ih, b_hh, w_att,
                                       h_last, s_i, s_j);
    rel_kernel<<<NN * 4, 256, 0, stream>>>(rel, w_att, b_att, s_i, s_j, temp);
    row_kernel<<<NN, 256, 0, stream>>>(temp, h_last, W_fc, b_fc, (float*)d_out);
}

// Round 3
// 97.808 us; speedup vs baseline: 1.6965x; 1.3440x over previous
//
#include <hip/hip_runtime.h>

#define NN 1024
#define DFEAT 6
#define TSTEPS 60
#define HID 64
#define RREL 60
#define SENT -1.0e30f

// -------- Fused kernel: blocks [0,1024) = GRU (dispatched first, latency-
// bound, hides under the stream); blocks [1024,5120) = rel stream (HBM-bound).
// The stream part is GRU-independent: it writes srel (or SENT if masked);
// s_i + s_j + b_att + leaky-relu are applied later in row_kernel.
__global__ __launch_bounds__(256) void fused_kernel(
    const float* __restrict__ x,      // (1024, 360)
    const float* __restrict__ W_ih,   // (192, 6)
    const float* __restrict__ W_hh,   // (192, 64)
    const float* __restrict__ b_ih,   // (192)
    const float* __restrict__ b_hh,   // (192)
    const float* __restrict__ w_att,  // (188)
    const float* __restrict__ rel,    // (1024, 1024, 60)
    float* __restrict__ h_last,       // (1024, 64)
    float* __restrict__ s_i,          // (1024)
    float* __restrict__ s_j,          // (1024)
    float* __restrict__ temp)         // (1024, 1024): srel or SENT
{
    if (blockIdx.x >= NN) {
        // ---------------- rel stream part ----------------
        const int b = blockIdx.x - NN;            // 0..4095
        const int i = b >> 2;
        const int j = ((b & 3) << 8) + threadIdx.x;
        const size_t pair = (size_t)i * NN + j;

        float wrel[RREL];                          // uniform -> scalar regs
#pragma unroll
        for (int r = 0; r < RREL; ++r) wrel[r] = w_att[2 * HID + r];

        const float4* rp = reinterpret_cast<const float4*>(rel + pair * RREL);
        float srel = 0.0f, msum = 0.0f;
#pragma unroll
        for (int r4 = 0; r4 < RREL / 4; ++r4) {
            float4 v = rp[r4];
            srel += v.x * wrel[4*r4+0] + v.y * wrel[4*r4+1]
                  + v.z * wrel[4*r4+2] + v.w * wrel[4*r4+3];
            msum += v.x + v.y + v.z + v.w;
        }
        temp[pair] = (msum != 0.0f) ? srel : SENT;
        return;
    }

    // ---------------- GRU part ----------------
    const int n = blockIdx.x;
    const int g = threadIdx.x;

    __shared__ __align__(16) float x_sh[DFEAT * TSTEPS];
    __shared__ __align__(16) float h_sh[HID];
    __shared__ float gi_sh[192];
    __shared__ float gh_sh[192];

    for (int idx = g; idx < DFEAT * TSTEPS; idx += 256)
        x_sh[idx] = x[(size_t)n * (DFEAT * TSTEPS) + idx];

    float whh[HID];
    float wih[DFEAT];
    float bih = 0.0f, bhh = 0.0f;
    if (g < 192) {
#pragma unroll
        for (int k4 = 0; k4 < HID / 4; ++k4) {
            float4 w = *reinterpret_cast<const float4*>(&W_hh[g * HID + k4 * 4]);
            whh[k4 * 4 + 0] = w.x; whh[k4 * 4 + 1] = w.y;
            whh[k4 * 4 + 2] = w.z; whh[k4 * 4 + 3] = w.w;
        }
#pragma unroll
        for (int d = 0; d < DFEAT; ++d) wih[d] = W_ih[g * DFEAT + d];
        bih = b_ih[g];
        bhh = b_hh[g];
    }

    if (g < HID) h_sh[g] = 0.0f;
    __syncthreads();

    for (int t = 0; t < TSTEPS; ++t) {
        if (g < 192) {
            float gi = bih;
#pragma unroll
            for (int d = 0; d < DFEAT; ++d) gi += x_sh[d * TSTEPS + t] * wih[d];

            float gh = bhh;
#pragma unroll
            for (int k4 = 0; k4 < HID / 4; ++k4) {
                float4 hv = *reinterpret_cast<const float4*>(&h_sh[k4 * 4]);
                gh += hv.x * whh[k4 * 4 + 0] + hv.y * whh[k4 * 4 + 1]
                    + hv.z * whh[k4 * 4 + 2] + hv.w * whh[k4 * 4 + 3];
            }
            gi_sh[g] = gi;
            gh_sh[g] = gh;
        }
        __syncthreads();

        if (g < HID) {
            float ir = gi_sh[g],        hr = gh_sh[g];
            float iz = gi_sh[HID + g],  hz = gh_sh[HID + g];
            float in_ = gi_sh[2*HID + g], hn = gh_sh[2*HID + g];
            float r = 1.0f / (1.0f + __expf(-(ir + hr)));
            float z = 1.0f / (1.0f + __expf(-(iz + hz)));
            float nn_ = tanhf(in_ + r * hn);
            float hold = h_sh[g];
            h_sh[g] = (1.0f - z) * nn_ + z * hold;
        }
        __syncthreads();
    }

    if (g < HID) {
        float hv = h_sh[g];
        h_last[(size_t)n * HID + g] = hv;
        float pi = hv * w_att[g];
        float pj = hv * w_att[HID + g];
#pragma unroll
        for (int off = 32; off > 0; off >>= 1) {
            pi += __shfl_down(pi, off);
            pj += __shfl_down(pj, off);
        }
        if (g == 0) { s_i[n] = pi; s_j[n] = pj; }
    }
}

// --------- Kernel 2: weight assembly + softmax + agg matvec + FC -------------
__global__ __launch_bounds__(256) void row_kernel(
    const float* __restrict__ temp,   // (1024, 1024): srel or SENT
    const float* __restrict__ s_i,    // (1024)
    const float* __restrict__ s_j,    // (1024)
    const float* __restrict__ b_att,  // (1)
    const float* __restrict__ h_last, // (1024, 64)
    const float* __restrict__ W_fc,   // (128)
    const float* __restrict__ b_fc,   // (1)
    float* __restrict__ out)          // (1024)
{
    const int i = blockIdx.x;
    const int tid = threadIdx.x;

    __shared__ __align__(16) float pm_sh[NN];
    __shared__ float red_sh[256];

    const float si_b = s_i[i] + b_att[0];
    float4 sv = reinterpret_cast<const float4*>(temp + (size_t)i * NN)[tid];
    float4 sj = reinterpret_cast<const float4*>(s_j)[tid];

    float tvv[4];
    {
        float srels[4] = {sv.x, sv.y, sv.z, sv.w};
        float sjs[4]   = {sj.x, sj.y, sj.z, sj.w};
#pragma unroll
        for (int c = 0; c < 4; ++c) {
            float w = si_b + sjs[c] + srels[c];
            w = (w >= 0.0f) ? w : 0.01f * w;
            float tv = (srels[c] != SENT) ? w : 0.0f;   // mask * weight
            tvv[c] = (tv == 0.0f) ? -10000.0f : tv;
        }
    }
    float m = fmaxf(fmaxf(tvv[0], tvv[1]), fmaxf(tvv[2], tvv[3]));
    red_sh[tid] = m;
    __syncthreads();
    for (int s = 128; s > 0; s >>= 1) {
        if (tid < s) red_sh[tid] = fmaxf(red_sh[tid], red_sh[tid + s]);
        __syncthreads();
    }
    const float M = red_sh[0];
    __syncthreads();

    float lsum = 0.0f;
    float4 pmv;
    {
        float e0 = __expf(tvv[0] - M), e1 = __expf(tvv[1] - M);
        float e2 = __expf(tvv[2] - M), e3 = __expf(tvv[3] - M);
        lsum = e0 + e1 + e2 + e3;                  // denom over ALL j
        pmv.x = (tvv[0] != -10000.0f) ? e0 : 0.0f;
        pmv.y = (tvv[1] != -10000.0f) ? e1 : 0.0f;
        pmv.z = (tvv[2] != -10000.0f) ? e2 : 0.0f;
        pmv.w = (tvv[3] != -10000.0f) ? e3 : 0.0f;
    }
    reinterpret_cast<float4*>(pm_sh)[tid] = pmv;

    red_sh[tid] = lsum;
    __syncthreads();
    for (int s = 128; s > 0; s >>= 1) {
        if (tid < s) red_sh[tid] += red_sh[tid + s];
        __syncthreads();
    }
    const float invS = 1.0f / red_sh[0];
    __syncthreads();

    // agg[h] = invS * sum_j pm[j] * h_last[j][h]
    const int h = tid & (HID - 1);
    const int grp = tid >> 6;                      // 4 groups x 256 j each
    float part = 0.0f;
    const float* hl = h_last + (size_t)grp * 256 * HID + h;
    const float* pm = pm_sh + grp * 256;
    for (int jc = 0; jc < 256; ++jc)
        part += pm[jc] * hl[(size_t)jc * HID];

    red_sh[tid] = part;
    __syncthreads();

    if (tid < HID) {
        float agg = (red_sh[tid] + red_sh[HID + tid]
                   + red_sh[2 * HID + tid] + red_sh[3 * HID + tid]) * invS;
        float o = h_last[(size_t)i * HID + tid] * W_fc[tid] + agg * W_fc[HID + tid];
#pragma unroll
        for (int off = 32; off > 0; off >>= 1) o += __shfl_down(o, off);
        if (tid == 0) out[i] = o + b_fc[0];
    }
}

extern "C" void kernel_launch(void* const* d_in, const int* in_sizes, int n_in,
                              void* d_out, int out_size, void* d_ws, size_t ws_size,
                              hipStream_t stream) {
    const float* x     = (const float*)d_in[0];
    const float* rel   = (const float*)d_in[1];
    const float* W_ih  = (const float*)d_in[2];
    const float* W_hh  = (const float*)d_in[3];
    const float* b_ih  = (const float*)d_in[4];
    const float* b_hh  = (const float*)d_in[5];
    const float* w_att = (const float*)d_in[6];
    const float* b_att = (const float*)d_in[7];
    const float* W_fc  = (const float*)d_in[8];
    const float* b_fc  = (const float*)d_in[9];

    float* ws     = (float*)d_ws;
    float* h_last = ws;                      // 1024*64
    float* s_i    = ws + NN * HID;           // 1024
    float* s_j    = ws + NN * HID + NN;      // 1024
    float* temp   = ws + NN * HID + 2 * NN;  // 1024*1024

    fused_kernel<<<NN + NN * 4, 256, 0, stream>>>(
        x, W_ih, W_hh, b_ih, b_hh, w_att, rel, h_last, s_i, s_j, temp);
    row_kernel<<<NN, 256, 0, stream>>>(temp, s_i, s_j, b_att, h_last,
                                       W_fc, b_fc, (float*)d_out);
}